// Round 3
// 59.370 us; speedup vs baseline: 1.0528x; 1.0528x over previous
//
#include <hip/hip_runtime.h>
#include <math.h>

#define N 10
#define C 4

// Single wave (64 lanes), fully parallel, LDS-only communication.
// vs the 62.5us baseline: the serial lane-0 insertion sort + NMS (runtime-
// indexed private arrays -> scratch, ~10k-cycle dependent-latency chain) is
// replaced by:
//  - lanes 0..39 produce boxes = outer(x,c); lanes 0..9 produce scores = r*x
//  - rank-based stable argsort: lane i's rank = #{s_j > s_i} + #{j<i: s_j==s_i}
//    (exactly jnp.argsort(-scores) stability), inverse-permute via LDS write
//  - NMS over sorted positions: lane p holds its offset box in registers;
//    box i is broadcast via same-address LDS reads (no conflict); keep[] lives
//    in LDS with a barrier per round (single wave: ~free), reproducing the
//    reference's sequential keep[i]-gated suppression exactly.
// No cross-lane builtins, no vector stores — only constructs the round-0
// baseline already ran on this harness. Zero scratch (rule #20): every
// runtime-indexed access goes through LDS hardware addressing.
__global__ __launch_bounds__(64, 1)
void Model_78056735637556_kernel(const float* __restrict__ x,
                                 const float* __restrict__ c,
                                 const float* __restrict__ r,
                                 float* __restrict__ out) {
    __shared__ float s_boxes[N][C];
    __shared__ float s_scores[N];
    __shared__ int   s_order[N];
    __shared__ int   s_keep[N];
    __shared__ float s_n[N][5];   // offset box n0..n3 + area, by sorted position

    const int t = threadIdx.x;
    const int i = t >> 2;   // row (valid for t < 40)
    const int k = t & 3;    // col

    // ---- produce boxes & scores ----
    if (t < N * C) s_boxes[i][k] = x[i] * c[k];
    if (t < N) { s_scores[t] = r[t] * x[t]; s_keep[t] = 1; }
    __syncthreads();

    // ---- stable descending rank (lanes 0..9, 10 broadcast LDS reads each) ----
    if (t < N) {
        const float s = s_scores[t];
        int rank = 0;
        #pragma unroll
        for (int j = 0; j < N; ++j) {
            const float sj = s_scores[j];
            rank += (sj > s) || ((sj == s) && (j < t));
        }
        s_order[rank] = t;   // inverse permutation via LDS dynamic write
    }
    __syncthreads();

    // ---- gather sorted box into registers, apply diagonal offset ----
    float n0 = 0.0f, n1 = 0.0f, n2 = 0.0f, n3 = 0.0f, ar = 0.0f;
    if (t < N) {
        // max over all 40 box values: unrolled constant-address broadcast reads
        float m = -INFINITY;
        #pragma unroll
        for (int ii = 0; ii < N; ++ii)
            #pragma unroll
            for (int kk = 0; kk < C; ++kk)
                m = fmaxf(m, s_boxes[ii][kk]);
        const float off = m + 1.0f;

        const int o = s_order[t];
        const float d = (float)o * off;   // offsets indexed by ORIGINAL row
        n0 = s_boxes[o][0] + d;
        n1 = s_boxes[o][1] + d;
        n2 = s_boxes[o][2] + d;
        n3 = s_boxes[o][3] + d;
        ar = (n2 - n0) * (n3 - n1);       // same op order as reference
        s_n[t][0] = n0; s_n[t][1] = n1; s_n[t][2] = n2; s_n[t][3] = n3;
        s_n[t][4] = ar;
    }
    __syncthreads();

    // ---- sequential suppression over sorted positions, parallel over j ----
    #pragma unroll
    for (int p = 0; p < N - 1; ++p) {
        if (t > p && t < N) {
            if (s_keep[p] && s_keep[t]) {   // keep[i] gate, current as of round p
                const float iw = fmaxf(fminf(s_n[p][2], n2) - fmaxf(s_n[p][0], n0), 0.0f);
                const float ih = fmaxf(fminf(s_n[p][3], n3) - fmaxf(s_n[p][1], n1), 0.0f);
                const float inter = iw * ih;
                const float iou = inter / (s_n[p][4] + ar - inter);
                if (iou > 0.0f) s_keep[t] = 0;  // NaN > 0 is false, same as JAX
            }
        }
        __syncthreads();   // uniform barrier: suppressions visible next round
    }

    // ---- write output: out[i][k] = keep[i] ? boxes[order[i]][k] : 0 ----
    if (t < N * C) {
        out[t] = s_keep[i] ? s_boxes[s_order[i]][k] : 0.0f;
    }
}

extern "C" void kernel_launch(void* const* d_in, const int* in_sizes, int n_in,
                              void* d_out, int out_size, void* d_ws, size_t ws_size,
                              hipStream_t stream) {
    const float* x = (const float*)d_in[0];
    const float* c = (const float*)d_in[1];
    const float* r = (const float*)d_in[2];
    float* out = (float*)d_out;
    Model_78056735637556_kernel<<<1, 64, 0, stream>>>(x, c, r, out);
}

// Round 4
// 57.886 us; speedup vs baseline: 1.0797x; 1.0256x over previous
//
#include <hip/hip_runtime.h>
#include <math.h>

#define N 10
#define C 4
#define NPAIR 45  // N*(N-1)/2

// Single wave, 3 barriers total. The NMS is split into:
//   (C) a fully PARALLEL pair phase — all 45 (p<j) IoU tests at once, each
//       setting bit j of s_mask[p] via LDS atomicOr when iou > 0;
//   (D) a wave-uniform register-only resolution — every lane reads the 10
//       masks (static unrolled) and replays the sequential keep-gating in
//       ~30 VALU cycles, so no barrier is needed to broadcast the result.
// This removes the previous version's 9 dependent LDS round-trips + 9
// barriers in the suppression loop. Semantics are exact: applying masks in
// ascending sorted order with the keep[p] gate reproduces the reference
// fori_loop; NaN IoU -> bit unset, same as (iou > 0) == false.
// Zero scratch (rule #20): every runtime-indexed access is LDS; the pair
// decode and mask resolution are fully unrolled selects over named registers.
__global__ __launch_bounds__(64, 1)
void Model_78056735637556_kernel(const float* __restrict__ x,
                                 const float* __restrict__ c,
                                 const float* __restrict__ r,
                                 float* __restrict__ out) {
    __shared__ float s_boxes[N][C];   // 16B rows, b128-friendly
    __shared__ float s_scores[N];
    __shared__ int   s_order[N];
    __shared__ int   s_mask[N];       // bit j of s_mask[p]: p suppresses j
    __shared__ float s_off;           // max_coord + 1

    const int t = threadIdx.x;

    // ---- Phase A: produce boxes & scores, init masks ----
    if (t < N * C) {
        const int i = t >> 2, k = t & 3;
        s_boxes[i][k] = x[i] * c[k];
    }
    if (t < N) { s_scores[t] = r[t] * x[t]; s_mask[t] = 0; }
    __syncthreads();  // barrier 1

    // ---- Phase B: stable descending rank (lanes 0..9) ∥ max (lane 10) ----
    if (t < N) {
        const float s = s_scores[t];
        int rank = 0;
        #pragma unroll
        for (int j = 0; j < N; ++j) {
            const float sj = s_scores[j];
            rank += (sj > s) || ((sj == s) && (j < t));
        }
        s_order[rank] = t;   // inverse permutation via LDS dynamic write
    }
    if (t == N) {            // idle lane computes max, overlapped with ranks
        float m = -INFINITY;
        #pragma unroll
        for (int ii = 0; ii < N; ++ii)
            #pragma unroll
            for (int kk = 0; kk < C; ++kk)
                m = fmaxf(m, s_boxes[ii][kk]);
        s_off = m + 1.0f;
    }
    __syncthreads();  // barrier 2

    // ---- Phase C: all 45 pairs in parallel ----
    if (t < NPAIR) {
        // triangular decode t -> (p, j), p<j: unrolled select chain (no
        // runtime-indexed private arrays)
        int p = 0, j = 1, acc = 0;
        #pragma unroll
        for (int pp = 0; pp < N - 1; ++pp) {
            const int cnt = N - 1 - pp;           // pairs in row pp
            const bool in = (t >= acc) && (t < acc + cnt);
            p = in ? pp : p;
            j = in ? (pp + 1 + (t - acc)) : j;
            acc += cnt;
        }

        const float off = s_off;
        const int op = s_order[p];
        const int oj = s_order[j];
        const float dp = (float)op * off;     // offsets indexed by ORIGINAL row
        const float dj = (float)oj * off;

        const float p0 = s_boxes[op][0] + dp, p1 = s_boxes[op][1] + dp;
        const float p2 = s_boxes[op][2] + dp, p3 = s_boxes[op][3] + dp;
        const float q0 = s_boxes[oj][0] + dj, q1 = s_boxes[oj][1] + dj;
        const float q2 = s_boxes[oj][2] + dj, q3 = s_boxes[oj][3] + dj;

        const float ap = (p2 - p0) * (p3 - p1);   // same op order as reference
        const float aq = (q2 - q0) * (q3 - q1);

        const float iw = fmaxf(fminf(p2, q2) - fmaxf(p0, q0), 0.0f);
        const float ih = fmaxf(fminf(p3, q3) - fmaxf(p1, q1), 0.0f);
        const float inter = iw * ih;
        const float iou = inter / (ap + aq - inter);

        if (iou > 0.0f)                  // NaN > 0 is false, same as JAX
            atomicOr(&s_mask[p], 1 << j);
    }
    __syncthreads();  // barrier 3

    // ---- Phase D: wave-uniform scalar resolution + output, no more barriers ----
    // Every lane replays the sequential suppression over registers.
    const int m0 = s_mask[0], m1 = s_mask[1], m2 = s_mask[2], m3 = s_mask[3];
    const int m4 = s_mask[4], m5 = s_mask[5], m6 = s_mask[6], m7 = s_mask[7];
    const int m8 = s_mask[8];            // row 9 suppresses nobody (no j > 9)
    int keep = (1 << N) - 1;
    if (keep & (1 << 0)) keep &= ~m0;
    if (keep & (1 << 1)) keep &= ~m1;
    if (keep & (1 << 2)) keep &= ~m2;
    if (keep & (1 << 3)) keep &= ~m3;
    if (keep & (1 << 4)) keep &= ~m4;
    if (keep & (1 << 5)) keep &= ~m5;
    if (keep & (1 << 6)) keep &= ~m6;
    if (keep & (1 << 7)) keep &= ~m7;
    if (keep & (1 << 8)) keep &= ~m8;

    // out[i][k] = keep[i] ? boxes[order[i]][k] : 0   (i = sorted position)
    if (t < N * C) {
        const int i = t >> 2, k = t & 3;
        out[t] = ((keep >> i) & 1) ? s_boxes[s_order[i]][k] : 0.0f;
    }
}

extern "C" void kernel_launch(void* const* d_in, const int* in_sizes, int n_in,
                              void* d_out, int out_size, void* d_ws, size_t ws_size,
                              hipStream_t stream) {
    const float* x = (const float*)d_in[0];
    const float* c = (const float*)d_in[1];
    const float* r = (const float*)d_in[2];
    float* out = (float*)d_out;
    Model_78056735637556_kernel<<<1, 64, 0, stream>>>(x, c, r, out);
}

// Round 5
// 56.701 us; speedup vs baseline: 1.1023x; 1.0209x over previous
//
#include <hip/hip_runtime.h>
#include <math.h>

#define N 10
#define C 4
#define NPAIR 45  // N*(N-1)/2

// Fully register-resident single wave: ZERO LDS, ZERO barriers, zero atomics.
// Every lane loads the whole problem (24 uniform-address scalar loads) and
// redundantly computes scores, the 40-box max, and the stable rank table in
// registers. The 45 IoU pair tests run one-per-lane and exchange their single
// bit via one __ballot; the triangular lane->(p,j) map is static, so every
// lane decodes the ballot into row masks with constant shifts and replays the
// sequential keep-resolution uniformly in ~30 scalar ops.
// Rule #20 discipline: every array access is compile-time-indexed after full
// unrolling; all runtime gathers (x[order[p]], c[k]) are cndmask select
// chains — zero scratch.
// FP semantics: offset-box coords computed with contraction OFF so mul+add
// matches the reference's separate outer-product and offset-add rounding
// (HIP defaults to -ffp-contract=fast; an fma here could flip a marginal
// IoU sign). Output boxes are the exact single mul x[o]*c[k].
__global__ __launch_bounds__(64, 1)
void Model_78056735637556_kernel(const float* __restrict__ x,
                                 const float* __restrict__ c,
                                 const float* __restrict__ r,
                                 float* __restrict__ out) {
    const int t = threadIdx.x;

    // ---- uniform loads: every lane holds the whole problem ----
    float xs[N], rs[N], cs[C];
    #pragma unroll
    for (int q = 0; q < N; ++q) xs[q] = x[q];
    #pragma unroll
    for (int q = 0; q < C; ++q) cs[q] = c[q];
    #pragma unroll
    for (int q = 0; q < N; ++q) rs[q] = r[q];

    // ---- scores ----
    float ss[N];
    #pragma unroll
    for (int q = 0; q < N; ++q) ss[q] = rs[q] * xs[q];

    // ---- max over all 40 box values ----
    float m = -INFINITY;
    #pragma unroll
    for (int iq = 0; iq < N; ++iq)
        #pragma unroll
        for (int kq = 0; kq < C; ++kq)
            m = fmaxf(m, xs[iq] * cs[kq]);
    const float off = m + 1.0f;

    // ---- stable descending ranks: rk[j] = #{q: s_q > s_j} + #{q<j: s_q == s_j}
    // For q<j this is (s_q >= s_j) with ordered-compare NaN semantics, which
    // matches (s_q > s_j) || (s_q == s_j) exactly (both false on NaN).
    int rk[N];
    #pragma unroll
    for (int j = 0; j < N; ++j) {
        int rank = 0;
        #pragma unroll
        for (int q = 0; q < N; ++q)
            rank += (q < j) ? (ss[q] >= ss[j]) : (ss[q] > ss[j]);
        rk[j] = rank;
    }

    // ---- static triangular decode: lane t -> pair (pp_, jj_), pp_ < jj_ ----
    int pp_ = 0, jj_ = 1;
    {
        int acc = 0;
        #pragma unroll
        for (int pq = 0; pq < N - 1; ++pq) {
            const int cnt = N - 1 - pq;
            const bool in = (t >= acc) && (t < acc + cnt);
            pp_ = in ? pq : pp_;
            jj_ = in ? (pq + 1 + (t - acc)) : jj_;
            acc += cnt;
        }
    }

    // ---- gather original index + x value at sorted positions pp_, jj_ ----
    int op = 0, oj = 0;
    float xop = 0.0f, xoj = 0.0f;
    #pragma unroll
    for (int q = 0; q < N; ++q) {
        const bool isp = (rk[q] == pp_);
        const bool isj = (rk[q] == jj_);
        op  = isp ? q     : op;
        xop = isp ? xs[q] : xop;
        oj  = isj ? q     : oj;
        xoj = isj ? xs[q] : xoj;
    }

    // ---- IoU of the offset boxes (contraction off: mul then add, like ref) ----
    bool sup;
    {
        #pragma clang fp contract(off)
        const float dp = (float)op * off;   // offsets indexed by ORIGINAL row
        const float dj = (float)oj * off;
        const float p0 = xop * cs[0] + dp, p1 = xop * cs[1] + dp;
        const float p2 = xop * cs[2] + dp, p3 = xop * cs[3] + dp;
        const float q0 = xoj * cs[0] + dj, q1 = xoj * cs[1] + dj;
        const float q2 = xoj * cs[2] + dj, q3 = xoj * cs[3] + dj;

        const float ap = (p2 - p0) * (p3 - p1);   // same op order as reference
        const float aq = (q2 - q0) * (q3 - q1);

        const float iw = fmaxf(fminf(p2, q2) - fmaxf(p0, q0), 0.0f);
        const float ih = fmaxf(fminf(p3, q3) - fmaxf(p1, q1), 0.0f);
        const float inter = iw * ih;
        const float iou = inter / (ap + aq - inter);

        sup = (t < NPAIR) && (iou > 0.0f);   // NaN > 0 false, same as JAX
    }

    // ---- one ballot: bit t of bal = pair t suppresses its j ----
    const unsigned long long bal = __ballot(sup);

    // ---- wave-uniform sequential keep resolution (row starts are static) ----
    int keep = (1 << N) - 1;
    #define ROW(P_, S_, L_)                                              \
        if (keep & (1 << (P_))) {                                        \
            const int bits = (int)((bal >> (S_)) & ((1ull << (L_)) - 1)); \
            keep &= ~(bits << ((P_) + 1));                               \
        }
    ROW(0,  0, 9) ROW(1,  9, 8) ROW(2, 17, 7) ROW(3, 24, 6) ROW(4, 30, 5)
    ROW(5, 35, 4) ROW(6, 39, 3) ROW(7, 42, 2) ROW(8, 44, 1)
    #undef ROW

    // ---- output: out[i][k] = keep[i] ? boxes[order[i]][k] : 0 ----
    if (t < N * C) {
        const int i = t >> 2, k = t & 3;
        // x at sorted position i (select chain, no runtime indexing)
        float xoi = 0.0f;
        #pragma unroll
        for (int q = 0; q < N; ++q)
            xoi = (rk[q] == i) ? xs[q] : xoi;
        // c[k] via select chain (k is runtime)
        float ck = cs[0];
        ck = (k == 1) ? cs[1] : ck;
        ck = (k == 2) ? cs[2] : ck;
        ck = (k == 3) ? cs[3] : ck;
        out[t] = ((keep >> i) & 1) ? xoi * ck : 0.0f;
    }
}

extern "C" void kernel_launch(void* const* d_in, const int* in_sizes, int n_in,
                              void* d_out, int out_size, void* d_ws, size_t ws_size,
                              hipStream_t stream) {
    const float* x = (const float*)d_in[0];
    const float* c = (const float*)d_in[1];
    const float* r = (const float*)d_in[2];
    float* out = (float*)d_out;
    Model_78056735637556_kernel<<<1, 64, 0, stream>>>(x, c, r, out);
}